// Round 2
// baseline (341.784 us; speedup 1.0000x reference)
//
#include <hip/hip_runtime.h>

#define LN_EPS 1e-5f

// Sizes fixed by the problem: B=32, TF=2048, C=32, D=8, HID=EG=32.
// rows = B*TF*C = 2,097,152 independent rows of 8 inputs -> 32 outputs.
//
// d_ws float layout:
//   [0,256)     M1 = A@W1   (32 x 8)
//   [256,288)   c1 = A@b1   (32)
//   [288,1312)  M2 = A@W2   (32 x 32)
//   [1312,1344) c2 = A@b2   (32)

typedef float f32x8 __attribute__((ext_vector_type(8)));

// Wave-uniform scalar loads: weights go to SGPRs (scalar cache), freeing the
// LDS pipe and VGPRs. s_waitcnt inside the asm keeps the data-dep safe.
__device__ __forceinline__ f32x8 sload8(const float* p) {
    f32x8 r;
    asm volatile("s_load_dwordx8 %0, %1, 0x0\n\ts_waitcnt lgkmcnt(0)"
                 : "=s"(r) : "s"(p));
    return r;
}

__global__ void gnn_prologue(const float* __restrict__ adjacency,
                             const float* __restrict__ W1,
                             const float* __restrict__ b1,
                             const float* __restrict__ W2,
                             const float* __restrict__ b2,
                             float* __restrict__ ws) {
    __shared__ float dis[32];
    __shared__ float na[32][32];
    const int t = threadIdx.x;
    if (t < 32) {
        float s = 1.0f;  // self-loop contributes 1 to the degree
        for (int j = 0; j < 32; ++j) s += adjacency[t * 32 + j];
        dis[t] = rsqrtf(s + 1e-6f);   // (deg + 1e-6)^-0.5
    }
    __syncthreads();
    for (int idx = t; idx < 1024; idx += blockDim.x) {
        const int i = idx >> 5, j = idx & 31;
        const float a = adjacency[idx] + (i == j ? 1.0f : 0.0f);
        na[i][j] = dis[i] * a * dis[j];
    }
    __syncthreads();
    // M2 = na @ W2   (W2 is [32,32] row-major: W2[j][k])
    for (int idx = t; idx < 1024; idx += blockDim.x) {
        const int i = idx >> 5, k = idx & 31;
        float a = 0.0f;
        for (int j = 0; j < 32; ++j) a += na[i][j] * W2[j * 32 + k];
        ws[288 + idx] = a;
    }
    // M1 = na @ W1   (W1 is [32,8] row-major: W1[j][d])
    for (int idx = t; idx < 256; idx += blockDim.x) {
        const int i = idx >> 3, d = idx & 7;
        float a = 0.0f;
        for (int j = 0; j < 32; ++j) a += na[i][j] * W1[j * 8 + d];
        ws[idx] = a;
    }
    // c1 = na @ b1, c2 = na @ b2
    if (t < 32) {
        float a1 = 0.0f, a2 = 0.0f;
        for (int j = 0; j < 32; ++j) {
            a1 += na[t][j] * b1[j];
            a2 += na[t][j] * b2[j];
        }
        ws[256 + t]  = a1;
        ws[1312 + t] = a2;
    }
}

__device__ __forceinline__ void ln32_sg(float* __restrict__ h,
                                        const float* __restrict__ gp,
                                        const float* __restrict__ bp) {
    float s = 0.0f;
#pragma unroll
    for (int i = 0; i < 32; ++i) s += h[i];
    const float m = s * 0.03125f;
    float v = 0.0f;
#pragma unroll
    for (int i = 0; i < 32; ++i) { const float d = h[i] - m; v = fmaf(d, d, v); }
    const float r = rsqrtf(v * 0.03125f + LN_EPS);
#pragma unroll
    for (int ii = 0; ii < 4; ++ii) {
        const f32x8 g = sload8(gp + ii * 8);
        const f32x8 b = sload8(bp + ii * 8);
#pragma unroll
        for (int j = 0; j < 8; ++j) {
            const int i = ii * 8 + j;
            h[i] = fmaf((h[i] - m) * r, g[j], b[j]);
        }
    }
}

__global__ __launch_bounds__(256, 4) void gnn_main(
        const float* __restrict__ x,
        const float* __restrict__ ws,
        const float* __restrict__ g1v, const float* __restrict__ be1v,
        const float* __restrict__ g2v, const float* __restrict__ be2v,
        float* __restrict__ out) {
    const int r = blockIdx.x * 256 + threadIdx.x;   // one row per thread

    const float4 p0 = ((const float4*)x)[r * 2];
    const float4 p1 = ((const float4*)x)[r * 2 + 1];
    const float xr[8] = {p0.x, p0.y, p0.z, p0.w, p1.x, p1.y, p1.z, p1.w};

    // stage 1: h = relu(M1 @ x + c1), weights via SGPR
    float h[32];
#pragma unroll
    for (int ii = 0; ii < 4; ++ii) {
        const f32x8 c1 = sload8(ws + 256 + ii * 8);
#pragma unroll
        for (int j = 0; j < 8; ++j) {
            const int i = ii * 8 + j;
            const f32x8 w = sload8(ws + i * 8);   // M1 row i (8 floats)
            float s = c1[j];
#pragma unroll
            for (int d = 0; d < 8; ++d) s = fmaf(xr[d], w[d], s);
            h[i] = fmaxf(s, 0.0f);
        }
    }
    ln32_sg(h, g1v, be1v);

    // stage 2: y = relu(M2 @ h + c2), weights via SGPR (4x sload8 per row)
    float y[32];
    const float* m2p = ws + 288;
#pragma unroll
    for (int ii = 0; ii < 4; ++ii) {
        const f32x8 c2 = sload8(ws + 1312 + ii * 8);
#pragma unroll
        for (int j = 0; j < 8; ++j) {
            const int i = ii * 8 + j;
            const f32x8 w0 = sload8(m2p + i * 32);
            const f32x8 w1 = sload8(m2p + i * 32 + 8);
            const f32x8 w2 = sload8(m2p + i * 32 + 16);
            const f32x8 w3 = sload8(m2p + i * 32 + 24);
            float s0 = c2[j], s1 = 0.0f;   // two chains to halve dep latency
#pragma unroll
            for (int k = 0; k < 8; ++k) {
                s0 = fmaf(h[k],      w0[k], s0);
                s1 = fmaf(h[k + 8],  w1[k], s1);
            }
#pragma unroll
            for (int k = 0; k < 8; ++k) {
                s0 = fmaf(h[k + 16], w2[k], s0);
                s1 = fmaf(h[k + 24], w3[k], s1);
            }
            y[i] = fmaxf(s0 + s1, 0.0f);
        }
    }
    ln32_sg(y, g2v, be2v);

    float4* ov = (float4*)out + (size_t)r * 8;
#pragma unroll
    for (int q = 0; q < 8; ++q)
        ov[q] = make_float4(y[q * 4], y[q * 4 + 1], y[q * 4 + 2], y[q * 4 + 3]);
}

extern "C" void kernel_launch(void* const* d_in, const int* in_sizes, int n_in,
                              void* d_out, int out_size, void* d_ws, size_t ws_size,
                              hipStream_t stream) {
    const float* x   = (const float*)d_in[0];
    const float* adj = (const float*)d_in[1];
    const float* W1  = (const float*)d_in[2];
    const float* b1  = (const float*)d_in[3];
    const float* W2  = (const float*)d_in[4];
    const float* b2  = (const float*)d_in[5];
    const float* g1  = (const float*)d_in[6];
    const float* be1 = (const float*)d_in[7];
    const float* g2  = (const float*)d_in[8];
    const float* be2 = (const float*)d_in[9];
    float* out = (float*)d_out;
    float* ws  = (float*)d_ws;

    gnn_prologue<<<1, 256, 0, stream>>>(adj, W1, b1, W2, b2, ws);

    const int rows = 32 * 2048 * 32;          // 2,097,152
    gnn_main<<<rows / 256, 256, 0, stream>>>(x, ws, g1, be1, g2, be2, out);
}

// Round 3
// 126.752 us; speedup vs baseline: 2.6965x; 2.6965x over previous
//
#include <hip/hip_runtime.h>

#define LN_EPS 1e-5f

// Sizes fixed by the problem: B=32, TF=2048, C=32, D=8, HID=EG=32.
// rows = B*TF*C = 2,097,152 independent rows: x[8] -> M1x+c1 -> relu -> LN ->
// M2'h+c2' -> relu -> LN -> *g2+be2. Adjacency + LN1 affine folded on device.
//
// d_ws float layout:
//   [0,256)     M1  = A@W1               (32 x 8)
//   [256,288)   c1  = A@b1               (32)
//   [288,1312)  M2' = (A@W2)*diag(g1)    (32 x 32, row-major [n][k])
//   [1312,1344) c2' = A@b2 + (A@W2)@be1  (32)
//   [1344,1376) g2
//   [1376,1408) be2

typedef float  f32x4  __attribute__((ext_vector_type(4)));
typedef __bf16 bf16x8 __attribute__((ext_vector_type(8)));

__global__ void gnn_prologue(const float* __restrict__ adjacency,
                             const float* __restrict__ W1,
                             const float* __restrict__ b1,
                             const float* __restrict__ W2,
                             const float* __restrict__ b2,
                             const float* __restrict__ g1,
                             const float* __restrict__ be1,
                             const float* __restrict__ g2,
                             const float* __restrict__ be2,
                             float* __restrict__ ws) {
    __shared__ float dis[32];
    __shared__ float na[32][32];
    __shared__ float m2t[32][32];
    const int t = threadIdx.x;
    if (t < 32) {
        float s = 1.0f;  // self-loop contributes 1 to the degree
        for (int j = 0; j < 32; ++j) s += adjacency[t * 32 + j];
        dis[t] = rsqrtf(s + 1e-6f);
    }
    __syncthreads();
    for (int idx = t; idx < 1024; idx += 256) {
        const int i = idx >> 5, j = idx & 31;
        const float a = adjacency[idx] + (i == j ? 1.0f : 0.0f);
        na[i][j] = dis[i] * a * dis[j];
    }
    __syncthreads();
    for (int idx = t; idx < 1024; idx += 256) {     // m2t = na @ W2
        const int i = idx >> 5, k = idx & 31;
        float a = 0.0f;
        for (int j = 0; j < 32; ++j) a += na[i][j] * W2[j * 32 + k];
        m2t[i][k] = a;
    }
    __syncthreads();
    for (int idx = t; idx < 1024; idx += 256)       // M2' = m2t * g1[k]
        ws[288 + idx] = m2t[idx >> 5][idx & 31] * g1[idx & 31];
    {
        const int i = t >> 3, d = t & 7;            // M1 = na @ W1
        float a = 0.0f;
        for (int j = 0; j < 32; ++j) a += na[i][j] * W1[j * 8 + d];
        ws[t] = a;
    }
    if (t < 32) {
        float a1 = 0.0f, a2 = 0.0f, a3 = 0.0f;
        for (int j = 0; j < 32; ++j) {
            a1 += na[t][j] * b1[j];
            a2 += na[t][j] * b2[j];
            a3 += m2t[t][j] * be1[j];
        }
        ws[256 + t]  = a1;          // c1
        ws[1312 + t] = a2 + a3;     // c2'
        ws[1344 + t] = g2[t];
        ws[1376 + t] = be2[t];
    }
}

// Main kernel: 256 threads = 4 waves; each wave owns 64 rows.
// Per-wave LDS scratch region wbuf[wave][2304] is used twice:
//   phase A: hbuf[64 rows][stride 36 floats]  (normalized h, fp32)
//   phase B: YT [32 cols][stride 68 floats]   (relu'd stage-2 out, fp32)
// Both strides chosen so every b128 access spreads perfectly over 32 banks.
__global__ __launch_bounds__(256, 4) void gnn_main(
        const float* __restrict__ x,
        const float* __restrict__ ws,
        float* __restrict__ out) {
    __shared__ float m1s[256];
    __shared__ float c1s[32], c2s[32], g2s[32], be2s[32];
    __shared__ float wbuf[4][2304];

    const int t    = threadIdx.x;
    const int wave = t >> 6;
    const int lane = t & 63;
    const int l15  = lane & 15;
    const int lg   = lane >> 4;
    float* const hb = &wbuf[wave][0];

    if (t < 256) m1s[t] = ws[t];
    if (t < 32) {
        c1s[t]  = ws[256 + t];
        c2s[t]  = ws[1312 + t];
        g2s[t]  = ws[1344 + t];
        be2s[t] = ws[1376 + t];
    }

    // B fragments (stage-2 weights), loaded once, held in VGPRs.
    // B[k][n] = M2'[n][k]; lane holds n = nt*16+l15, k = lg*8 + i.
    // hi/lo bf16 split so the 3-term MFMA sum is fp32-accurate.
    bf16x8 bhi[2], blo[2];
#pragma unroll
    for (int nt = 0; nt < 2; ++nt) {
        const float* bp = ws + 288 + (nt * 16 + l15) * 32 + lg * 8;
#pragma unroll
        for (int i = 0; i < 8; ++i) {
            const float w  = bp[i];
            const __bf16 h = (__bf16)w;
            bhi[nt][i] = h;
            blo[nt][i] = (__bf16)(w - (float)h);
        }
    }
    __syncthreads();

    const int row_g = blockIdx.x * 256 + t;     // one row per thread
    const float4 p0 = ((const float4*)x)[row_g * 2];
    const float4 p1 = ((const float4*)x)[row_g * 2 + 1];
    const float xr[8] = {p0.x, p0.y, p0.z, p0.w, p1.x, p1.y, p1.z, p1.w};

    // stage 1: h = relu(M1 @ x + c1), fp32 in-thread
    float h[32];
#pragma unroll
    for (int i = 0; i < 32; ++i) {
        float s = c1s[i];
#pragma unroll
        for (int d = 0; d < 8; ++d) s = fmaf(xr[d], m1s[i * 8 + d], s);
        h[i] = fmaxf(s, 0.0f);
    }
    // LN1 normalize only (affine folded into M2'/c2')
    {
        float s = 0.0f;
#pragma unroll
        for (int i = 0; i < 32; ++i) s += h[i];
        const float m = s * 0.03125f;
        float v = 0.0f;
#pragma unroll
        for (int i = 0; i < 32; ++i) { const float d = h[i] - m; v = fmaf(d, d, v); }
        const float r = rsqrtf(v * 0.03125f + LN_EPS);
        float* dst = hb + lane * 36;            // 144 B stride: conflict-perfect
#pragma unroll
        for (int c = 0; c < 8; ++c) {
            ((float4*)dst)[c] = make_float4((h[c * 4 + 0] - m) * r, (h[c * 4 + 1] - m) * r,
                                            (h[c * 4 + 2] - m) * r, (h[c * 4 + 3] - m) * r);
        }
    }
    __syncthreads();

    // A fragments: A[m][k] = hhat[mt*16+m][k]; lane holds m=l15, k=lg*8+i.
    bf16x8 ahi[4], alo[4];
#pragma unroll
    for (int mt = 0; mt < 4; ++mt) {
        const float* ap = hb + (mt * 16 + l15) * 36 + lg * 8;
        const float4 a0 = ((const float4*)ap)[0];
        const float4 a1 = ((const float4*)ap)[1];
        const float av[8] = {a0.x, a0.y, a0.z, a0.w, a1.x, a1.y, a1.z, a1.w};
#pragma unroll
        for (int i = 0; i < 8; ++i) {
            const __bf16 hi = (__bf16)av[i];
            ahi[mt][i] = hi;
            alo[mt][i] = (__bf16)(av[i] - (float)hi);
        }
    }
    __syncthreads();   // all A-frag reads landed before wbuf is overwritten as YT

    // stage 2 MFMA: 4 m-tiles x 2 n-tiles, 3-term split each; relu; YT write.
#pragma unroll
    for (int mt = 0; mt < 4; ++mt) {
#pragma unroll
        for (int nt = 0; nt < 2; ++nt) {
            const float c2v = c2s[nt * 16 + l15];
            f32x4 acc = {c2v, c2v, c2v, c2v};
            acc = __builtin_amdgcn_mfma_f32_16x16x32_bf16(ahi[mt], bhi[nt], acc, 0, 0, 0);
            acc = __builtin_amdgcn_mfma_f32_16x16x32_bf16(alo[mt], bhi[nt], acc, 0, 0, 0);
            acc = __builtin_amdgcn_mfma_f32_16x16x32_bf16(ahi[mt], blo[nt], acc, 0, 0, 0);
            // D reg j -> row (lane>>4)*4 + j, col lane&15  (verified C/D layout)
            float* yt = hb + (nt * 16 + l15) * 68 + mt * 16 + lg * 4;   // 272 B stride
            *((float4*)yt) = make_float4(fmaxf(acc[0], 0.0f), fmaxf(acc[1], 0.0f),
                                         fmaxf(acc[2], 0.0f), fmaxf(acc[3], 0.0f));
        }
    }
    __syncthreads();

    // LN2 read-back: lane reads its own row (2 lanes/bank -> conflict-free)
    float y[32];
#pragma unroll
    for (int c = 0; c < 32; ++c) y[c] = hb[c * 68 + lane];
    float s = 0.0f;
#pragma unroll
    for (int i = 0; i < 32; ++i) s += y[i];
    const float m = s * 0.03125f;
    float v = 0.0f;
#pragma unroll
    for (int i = 0; i < 32; ++i) { const float d = y[i] - m; v = fmaf(d, d, v); }
    const float r = rsqrtf(v * 0.03125f + LN_EPS);

    float4* ov = (float4*)out + (size_t)row_g * 8;
#pragma unroll
    for (int q = 0; q < 8; ++q) {
        ov[q] = make_float4(fmaf((y[q * 4 + 0] - m) * r, g2s[q * 4 + 0], be2s[q * 4 + 0]),
                            fmaf((y[q * 4 + 1] - m) * r, g2s[q * 4 + 1], be2s[q * 4 + 1]),
                            fmaf((y[q * 4 + 2] - m) * r, g2s[q * 4 + 2], be2s[q * 4 + 2]),
                            fmaf((y[q * 4 + 3] - m) * r, g2s[q * 4 + 3], be2s[q * 4 + 3]));
    }
}

extern "C" void kernel_launch(void* const* d_in, const int* in_sizes, int n_in,
                              void* d_out, int out_size, void* d_ws, size_t ws_size,
                              hipStream_t stream) {
    const float* x   = (const float*)d_in[0];
    const float* adj = (const float*)d_in[1];
    const float* W1  = (const float*)d_in[2];
    const float* b1  = (const float*)d_in[3];
    const float* W2  = (const float*)d_in[4];
    const float* b2  = (const float*)d_in[5];
    const float* g1  = (const float*)d_in[6];
    const float* be1 = (const float*)d_in[7];
    const float* g2  = (const float*)d_in[8];
    const float* be2 = (const float*)d_in[9];
    float* out = (float*)d_out;
    float* ws  = (float*)d_ws;

    gnn_prologue<<<1, 256, 0, stream>>>(adj, W1, b1, W2, b2, g1, be1, g2, be2, ws);

    const int rows = 32 * 2048 * 32;            // 2,097,152
    gnn_main<<<rows / 256, 256, 0, stream>>>(x, ws, out);
}

// Round 4
// 121.301 us; speedup vs baseline: 2.8176x; 1.0449x over previous
//
#include <hip/hip_runtime.h>

#define LN_EPS 1e-5f

// Sizes fixed by the problem: B=32, TF=2048, C=32, D=8, HID=EG=32.
// rows = B*TF*C = 2,097,152 independent rows: x[8] -> M1x+c1 -> relu -> LN ->
// M2'h+c2' -> relu -> LN -> *g2+be2. Adjacency + LN1 affine folded on device.
//
// d_ws float layout:
//   [0,256)     M1  = A@W1               (32 x 8)
//   [256,288)   c1  = A@b1               (32)
//   [288,1312)  M2' = (A@W2)*diag(g1)    (32 x 32, row-major [n][k])
//   [1312,1344) c2' = A@b2 + (A@W2)@be1  (32)
//   [1344,1376) g2
//   [1376,1408) be2

typedef float  f32x4  __attribute__((ext_vector_type(4)));
typedef __bf16 bf16x8 __attribute__((ext_vector_type(8)));

__global__ void gnn_prologue(const float* __restrict__ adjacency,
                             const float* __restrict__ W1,
                             const float* __restrict__ b1,
                             const float* __restrict__ W2,
                             const float* __restrict__ b2,
                             const float* __restrict__ g1,
                             const float* __restrict__ be1,
                             const float* __restrict__ g2,
                             const float* __restrict__ be2,
                             float* __restrict__ ws) {
    __shared__ float dis[32];
    __shared__ float na[32][32];
    __shared__ float m2t[32][32];
    const int t = threadIdx.x;
    if (t < 32) {
        float s = 1.0f;  // self-loop contributes 1 to the degree
        for (int j = 0; j < 32; ++j) s += adjacency[t * 32 + j];
        dis[t] = rsqrtf(s + 1e-6f);
    }
    __syncthreads();
    for (int idx = t; idx < 1024; idx += 256) {
        const int i = idx >> 5, j = idx & 31;
        const float a = adjacency[idx] + (i == j ? 1.0f : 0.0f);
        na[i][j] = dis[i] * a * dis[j];
    }
    __syncthreads();
    for (int idx = t; idx < 1024; idx += 256) {     // m2t = na @ W2
        const int i = idx >> 5, k = idx & 31;
        float a = 0.0f;
        for (int j = 0; j < 32; ++j) a += na[i][j] * W2[j * 32 + k];
        m2t[i][k] = a;
    }
    __syncthreads();
    for (int idx = t; idx < 1024; idx += 256)       // M2' = m2t * g1[k]
        ws[288 + idx] = m2t[idx >> 5][idx & 31] * g1[idx & 31];
    {
        const int i = t >> 3, d = t & 7;            // M1 = na @ W1
        float a = 0.0f;
        for (int j = 0; j < 32; ++j) a += na[i][j] * W1[j * 8 + d];
        ws[t] = a;
    }
    if (t < 32) {
        float a1 = 0.0f, a2 = 0.0f, a3 = 0.0f;
        for (int j = 0; j < 32; ++j) {
            a1 += na[t][j] * b1[j];
            a2 += na[t][j] * b2[j];
            a3 += m2t[t][j] * be1[j];
        }
        ws[256 + t]  = a1;          // c1
        ws[1312 + t] = a2 + a3;     // c2'
        ws[1344 + t] = g2[t];
        ws[1376 + t] = be2[t];
    }
}

// Main kernel: 256 threads = 4 waves; each wave owns 64 rows.
// Weights/params are read straight from global ws at compile-time-constant
// offsets (wave-uniform -> scalar loads / L1-broadcast VMEM), NOT via LDS:
// the LDS pipe carries only the two genuine transposes + LN2 readback.
// Per-wave LDS scratch wbuf[wave][2304] is used twice:
//   phase A: hbuf[64 rows][stride 36 floats]  (normalized h, fp32)
//   phase B: YT [32 cols][stride 68 floats]   (relu'd stage-2 out, fp32)
__global__ __launch_bounds__(256, 4) void gnn_main(
        const float* __restrict__ x,
        const float* __restrict__ ws,
        float* __restrict__ out) {
    __shared__ float wbuf[4][2304];

    const int t    = threadIdx.x;
    const int wave = t >> 6;
    const int lane = t & 63;
    const int l15  = lane & 15;
    const int lg   = lane >> 4;
    float* const hb = &wbuf[wave][0];

    // B fragments (stage-2 weights), loaded once from global, held in VGPRs.
    // B[k][n] = M2'[n][k]; lane holds n = nt*16+l15, k = lg*8 + i.
    // hi/lo bf16 split so the 3-term MFMA sum is fp32-accurate.
    bf16x8 bhi[2], blo[2];
#pragma unroll
    for (int nt = 0; nt < 2; ++nt) {
        const float* bp = ws + 288 + (nt * 16 + l15) * 32 + lg * 8;
#pragma unroll
        for (int i = 0; i < 8; ++i) {
            const float w  = bp[i];
            const __bf16 h = (__bf16)w;
            bhi[nt][i] = h;
            blo[nt][i] = (__bf16)(w - (float)h);
        }
    }
    // lane-dependent c2' entries, hoisted (2 L1-hit loads)
    const float c2a = ws[1312 + l15];
    const float c2b = ws[1312 + 16 + l15];

    const int row_g = blockIdx.x * 256 + t;     // one row per thread
    const float4 p0 = ((const float4*)x)[row_g * 2];
    const float4 p1 = ((const float4*)x)[row_g * 2 + 1];
    const float xr[8] = {p0.x, p0.y, p0.z, p0.w, p1.x, p1.y, p1.z, p1.w};

    // stage 1: h = relu(M1 @ x + c1); weights at constant uniform offsets
    float h[32];
#pragma unroll
    for (int i = 0; i < 32; ++i) {
        float s = ws[256 + i];
#pragma unroll
        for (int d = 0; d < 8; ++d) s = fmaf(xr[d], ws[i * 8 + d], s);
        h[i] = fmaxf(s, 0.0f);
    }
    // LN1 normalize only (affine folded into M2'/c2')
    {
        float s = 0.0f;
#pragma unroll
        for (int i = 0; i < 32; ++i) s += h[i];
        const float m = s * 0.03125f;
        float v = 0.0f;
#pragma unroll
        for (int i = 0; i < 32; ++i) { const float d = h[i] - m; v = fmaf(d, d, v); }
        const float r = rsqrtf(v * 0.03125f + LN_EPS);
        float* dst = hb + lane * 36;            // 144 B stride: conflict-perfect
#pragma unroll
        for (int c = 0; c < 8; ++c) {
            ((float4*)dst)[c] = make_float4((h[c * 4 + 0] - m) * r, (h[c * 4 + 1] - m) * r,
                                            (h[c * 4 + 2] - m) * r, (h[c * 4 + 3] - m) * r);
        }
    }
    __syncthreads();

    // A fragments: A[m][k] = hhat[mt*16+m][k]; lane holds m=l15, k=lg*8+i.
    bf16x8 ahi[4], alo[4];
#pragma unroll
    for (int mt = 0; mt < 4; ++mt) {
        const float* ap = hb + (mt * 16 + l15) * 36 + lg * 8;
        const float4 a0 = ((const float4*)ap)[0];
        const float4 a1 = ((const float4*)ap)[1];
        const float av[8] = {a0.x, a0.y, a0.z, a0.w, a1.x, a1.y, a1.z, a1.w};
#pragma unroll
        for (int i = 0; i < 8; ++i) {
            const __bf16 hi = (__bf16)av[i];
            ahi[mt][i] = hi;
            alo[mt][i] = (__bf16)(av[i] - (float)hi);
        }
    }
    __syncthreads();   // all A-frag reads landed before wbuf is overwritten as YT

    // stage 2 MFMA: 4 m-tiles x 2 n-tiles, 3-term split each; relu; YT write.
#pragma unroll
    for (int mt = 0; mt < 4; ++mt) {
#pragma unroll
        for (int nt = 0; nt < 2; ++nt) {
            const float c2v = nt ? c2b : c2a;
            f32x4 acc = {c2v, c2v, c2v, c2v};
            acc = __builtin_amdgcn_mfma_f32_16x16x32_bf16(ahi[mt], bhi[nt], acc, 0, 0, 0);
            acc = __builtin_amdgcn_mfma_f32_16x16x32_bf16(alo[mt], bhi[nt], acc, 0, 0, 0);
            acc = __builtin_amdgcn_mfma_f32_16x16x32_bf16(ahi[mt], blo[nt], acc, 0, 0, 0);
            // D reg j -> row (lane>>4)*4 + j, col lane&15  (verified C/D layout)
            float* yt = hb + (nt * 16 + l15) * 68 + mt * 16 + lg * 4;   // 272 B stride
            *((float4*)yt) = make_float4(fmaxf(acc[0], 0.0f), fmaxf(acc[1], 0.0f),
                                         fmaxf(acc[2], 0.0f), fmaxf(acc[3], 0.0f));
        }
    }
    __syncthreads();

    // LN2 read-back: lane reads its own row (2 lanes/bank -> conflict-free)
    float y[32];
#pragma unroll
    for (int c = 0; c < 32; ++c) y[c] = hb[c * 68 + lane];
    float s = 0.0f;
#pragma unroll
    for (int i = 0; i < 32; ++i) s += y[i];
    const float m = s * 0.03125f;
    float v = 0.0f;
#pragma unroll
    for (int i = 0; i < 32; ++i) { const float d = y[i] - m; v = fmaf(d, d, v); }
    const float r = rsqrtf(v * 0.03125f + LN_EPS);

    float4* ov = (float4*)out + (size_t)row_g * 8;
#pragma unroll
    for (int q = 0; q < 8; ++q) {
        ov[q] = make_float4(fmaf((y[q * 4 + 0] - m) * r, ws[1344 + q * 4 + 0], ws[1376 + q * 4 + 0]),
                            fmaf((y[q * 4 + 1] - m) * r, ws[1344 + q * 4 + 1], ws[1376 + q * 4 + 1]),
                            fmaf((y[q * 4 + 2] - m) * r, ws[1344 + q * 4 + 2], ws[1376 + q * 4 + 2]),
                            fmaf((y[q * 4 + 3] - m) * r, ws[1344 + q * 4 + 3], ws[1376 + q * 4 + 3]));
    }
}

extern "C" void kernel_launch(void* const* d_in, const int* in_sizes, int n_in,
                              void* d_out, int out_size, void* d_ws, size_t ws_size,
                              hipStream_t stream) {
    const float* x   = (const float*)d_in[0];
    const float* adj = (const float*)d_in[1];
    const float* W1  = (const float*)d_in[2];
    const float* b1  = (const float*)d_in[3];
    const float* W2  = (const float*)d_in[4];
    const float* b2  = (const float*)d_in[5];
    const float* g1  = (const float*)d_in[6];
    const float* be1 = (const float*)d_in[7];
    const float* g2  = (const float*)d_in[8];
    const float* be2 = (const float*)d_in[9];
    float* out = (float*)d_out;
    float* ws  = (float*)d_ws;

    gnn_prologue<<<1, 256, 0, stream>>>(adj, W1, b1, W2, b2, g1, be1, g2, be2, ws);

    const int rows = 32 * 2048 * 32;            // 2,097,152
    gnn_main<<<rows / 256, 256, 0, stream>>>(x, ws, out);
}

// Round 5
// 119.098 us; speedup vs baseline: 2.8698x; 1.0185x over previous
//
#include <hip/hip_runtime.h>

#define LN_EPS 1e-5f

// Sizes fixed by the problem: B=32, TF=2048, C=32, D=8, HID=EG=32.
// rows = B*TF*C = 2,097,152 independent rows: x[8] -> M1x+c1 -> relu -> LN ->
// M2'h+c2' -> relu -> LN -> *g2+be2. Adjacency + LN1 affine folded on device.
//
// d_ws layout (float indices):
//   [0,256)     M1  = A@W1               (32 x 8)
//   [256,288)   c1  = A@b1               (32)
//   [288,1312)  M2' = (A@W2)*diag(g1)    (32 x 32, row-major [n][k])
//   [1312,1344) c2' = A@b2 + (A@W2)@be1  (32)
//   [1344,1376) g2
//   [1376,1408) be2
//   [1408,1920) baked B-frag region, bf16 (see below): bhi at byte 5632,
//               blo at byte 7680; slot (nt,l15,lg) = 16 bytes of 8 bf16.

typedef float  f32x4  __attribute__((ext_vector_type(4)));
typedef __bf16 bf16x8 __attribute__((ext_vector_type(8)));

__global__ void gnn_prologue(const float* __restrict__ adjacency,
                             const float* __restrict__ W1,
                             const float* __restrict__ b1,
                             const float* __restrict__ W2,
                             const float* __restrict__ b2,
                             const float* __restrict__ g1,
                             const float* __restrict__ be1,
                             const float* __restrict__ g2,
                             const float* __restrict__ be2,
                             float* __restrict__ ws) {
    __shared__ float dis[32];
    __shared__ float na[32][32];
    __shared__ float m2t[32][32];
    const int t = threadIdx.x;
    if (t < 32) {
        float s = 1.0f;  // self-loop contributes 1 to the degree
        for (int j = 0; j < 32; ++j) s += adjacency[t * 32 + j];
        dis[t] = rsqrtf(s + 1e-6f);
    }
    __syncthreads();
    for (int idx = t; idx < 1024; idx += 256) {
        const int i = idx >> 5, j = idx & 31;
        const float a = adjacency[idx] + (i == j ? 1.0f : 0.0f);
        na[i][j] = dis[i] * a * dis[j];
    }
    __syncthreads();
    for (int idx = t; idx < 1024; idx += 256) {     // m2t = na @ W2
        const int i = idx >> 5, k = idx & 31;
        float a = 0.0f;
        for (int j = 0; j < 32; ++j) a += na[i][j] * W2[j * 32 + k];
        m2t[i][k] = a;
    }
    __syncthreads();
    for (int idx = t; idx < 1024; idx += 256)       // M2' = m2t * g1[k]
        ws[288 + idx] = m2t[idx >> 5][idx & 31] * g1[idx & 31];
    {
        const int i = t >> 3, d = t & 7;            // M1 = na @ W1
        float a = 0.0f;
        for (int j = 0; j < 32; ++j) a += na[i][j] * W1[j * 8 + d];
        ws[t] = a;
    }
    if (t < 32) {
        float a1 = 0.0f, a2 = 0.0f, a3 = 0.0f;
        for (int j = 0; j < 32; ++j) {
            a1 += na[t][j] * b1[j];
            a2 += na[t][j] * b2[j];
            a3 += m2t[t][j] * be1[j];
        }
        ws[256 + t]  = a1;          // c1
        ws[1312 + t] = a2 + a3;     // c2'
        ws[1344 + t] = g2[t];
        ws[1376 + t] = be2[t];
    }
    // Bake B fragments: B[k][n] = M2'[n][k]; slot (nt, l15, lg) holds
    // k = lg*8 + i (i=0..7) for n = nt*16 + l15, split into bf16 hi/lo.
    // ushort index: hi at 2816 + slot*8 + i, lo at 3840 + slot*8 + i.
    if (t < 128) {
        const int nt  = t >> 6;
        const int l15 = (t >> 2) & 15;
        const int lg  = t & 3;
        const int n   = nt * 16 + l15;
        unsigned short* wsu = (unsigned short*)ws;
        for (int i = 0; i < 8; ++i) {
            const float w  = m2t[n][lg * 8 + i] * g1[lg * 8 + i];
            const __bf16 h = (__bf16)w;
            const __bf16 l = (__bf16)(w - (float)h);
            wsu[2816 + t * 8 + i] = __builtin_bit_cast(unsigned short, h);
            wsu[3840 + t * 8 + i] = __builtin_bit_cast(unsigned short, l);
        }
    }
}

// Main kernel: 256 threads = 4 waves; each wave owns 64 rows.
// Weights/params read from global ws at compile-time-constant uniform offsets
// (scalar loads / L1 broadcast); B-frags pre-baked bf16 (one 16B load each).
// Per-wave LDS scratch wbuf[wave][2304] is used twice:
//   phase A: hbuf[64 rows][stride 36 floats]  (normalized h, fp32)
//   phase B: YT [32 cols][stride 68 floats]   (relu'd stage-2 out, fp32)
__global__ __launch_bounds__(256, 4) void gnn_main(
        const float* __restrict__ x,
        const float* __restrict__ ws,
        float* __restrict__ out) {
    __shared__ float wbuf[4][2304];

    const int t    = threadIdx.x;
    const int wave = t >> 6;
    const int lane = t & 63;
    const int l15  = lane & 15;
    const int lg   = lane >> 4;
    float* const hb = &wbuf[wave][0];

    // B fragments: baked bf16 hi/lo, one dwordx4 load each, zero cvt VALU.
    const unsigned short* wsu = (const unsigned short*)ws;
    const int slot8 = ((lane >> 4) + ((lane & 15) << 2)) * 8;  // (l15*4+lg)*8
    bf16x8 bhi[2], blo[2];
    bhi[0] = *(const bf16x8*)(wsu + 2816 + slot8);
    bhi[1] = *(const bf16x8*)(wsu + 2816 + 512 + slot8);
    blo[0] = *(const bf16x8*)(wsu + 3840 + slot8);
    blo[1] = *(const bf16x8*)(wsu + 3840 + 512 + slot8);
    // lane-dependent c2' entries, hoisted (2 L1-hit loads)
    const float c2a = ws[1312 + l15];
    const float c2b = ws[1312 + 16 + l15];

    const int row_g = blockIdx.x * 256 + t;     // one row per thread
    const float4 p0 = ((const float4*)x)[row_g * 2];
    const float4 p1 = ((const float4*)x)[row_g * 2 + 1];
    const float xr[8] = {p0.x, p0.y, p0.z, p0.w, p1.x, p1.y, p1.z, p1.w};

    // stage 1: h = relu(M1 @ x + c1); weights at constant uniform offsets
    float h[32];
#pragma unroll
    for (int i = 0; i < 32; ++i) {
        float s = ws[256 + i];
#pragma unroll
        for (int d = 0; d < 8; ++d) s = fmaf(xr[d], ws[i * 8 + d], s);
        h[i] = fmaxf(s, 0.0f);
    }
    // LN1 normalize only (affine folded into M2'/c2'); fused single-pass
    // moments with 4-way tree partials (short dep chains).
    {
        float s0 = 0, s1 = 0, s2 = 0, s3 = 0, q0 = 0, q1 = 0, q2 = 0, q3 = 0;
#pragma unroll
        for (int i = 0; i < 32; i += 4) {
            s0 += h[i];     q0 = fmaf(h[i],     h[i],     q0);
            s1 += h[i + 1]; q1 = fmaf(h[i + 1], h[i + 1], q1);
            s2 += h[i + 2]; q2 = fmaf(h[i + 2], h[i + 2], q2);
            s3 += h[i + 3]; q3 = fmaf(h[i + 3], h[i + 3], q3);
        }
        const float m   = ((s0 + s1) + (s2 + s3)) * 0.03125f;
        const float msq = ((q0 + q1) + (q2 + q3)) * 0.03125f;
        const float r   = rsqrtf(fmaf(-m, m, msq) + LN_EPS);
        float* dst = hb + lane * 36;            // 144 B stride: conflict-perfect
#pragma unroll
        for (int c = 0; c < 8; ++c) {
            ((float4*)dst)[c] = make_float4((h[c * 4 + 0] - m) * r, (h[c * 4 + 1] - m) * r,
                                            (h[c * 4 + 2] - m) * r, (h[c * 4 + 3] - m) * r);
        }
    }
    __syncthreads();

    // A fragments: A[m][k] = hhat[mt*16+m][k]; lane holds m=l15, k=lg*8+i.
    bf16x8 ahi[4], alo[4];
#pragma unroll
    for (int mt = 0; mt < 4; ++mt) {
        const float* ap = hb + (mt * 16 + l15) * 36 + lg * 8;
        const float4 a0 = ((const float4*)ap)[0];
        const float4 a1 = ((const float4*)ap)[1];
        const float av[8] = {a0.x, a0.y, a0.z, a0.w, a1.x, a1.y, a1.z, a1.w};
#pragma unroll
        for (int i = 0; i < 8; ++i) {
            const __bf16 hi = (__bf16)av[i];
            ahi[mt][i] = hi;
            alo[mt][i] = (__bf16)(av[i] - (float)hi);
        }
    }
    __syncthreads();   // all A-frag reads landed before wbuf is overwritten as YT

    // stage 2 MFMA: 4 m-tiles x 2 n-tiles, 3-term split each; relu; YT write.
#pragma unroll
    for (int mt = 0; mt < 4; ++mt) {
#pragma unroll
        for (int nt = 0; nt < 2; ++nt) {
            const float c2v = nt ? c2b : c2a;
            f32x4 acc = {c2v, c2v, c2v, c2v};
            acc = __builtin_amdgcn_mfma_f32_16x16x32_bf16(ahi[mt], bhi[nt], acc, 0, 0, 0);
            acc = __builtin_amdgcn_mfma_f32_16x16x32_bf16(alo[mt], bhi[nt], acc, 0, 0, 0);
            acc = __builtin_amdgcn_mfma_f32_16x16x32_bf16(ahi[mt], blo[nt], acc, 0, 0, 0);
            // D reg j -> row (lane>>4)*4 + j, col lane&15  (verified C/D layout)
            float* yt = hb + (nt * 16 + l15) * 68 + mt * 16 + lg * 4;   // 272 B stride
            *((float4*)yt) = make_float4(fmaxf(acc[0], 0.0f), fmaxf(acc[1], 0.0f),
                                         fmaxf(acc[2], 0.0f), fmaxf(acc[3], 0.0f));
        }
    }
    __syncthreads();

    // LN2 read-back: lane reads its own row (2 lanes/bank -> conflict-free);
    // fused single-pass moments with tree partials.
    float y[32];
#pragma unroll
    for (int c = 0; c < 32; ++c) y[c] = hb[c * 68 + lane];
    float s0 = 0, s1 = 0, s2 = 0, s3 = 0, q0 = 0, q1 = 0, q2 = 0, q3 = 0;
#pragma unroll
    for (int i = 0; i < 32; i += 4) {
        s0 += y[i];     q0 = fmaf(y[i],     y[i],     q0);
        s1 += y[i + 1]; q1 = fmaf(y[i + 1], y[i + 1], q1);
        s2 += y[i + 2]; q2 = fmaf(y[i + 2], y[i + 2], q2);
        s3 += y[i + 3]; q3 = fmaf(y[i + 3], y[i + 3], q3);
    }
    const float m   = ((s0 + s1) + (s2 + s3)) * 0.03125f;
    const float msq = ((q0 + q1) + (q2 + q3)) * 0.03125f;
    const float r   = rsqrtf(fmaf(-m, m, msq) + LN_EPS);

    float4* ov = (float4*)out + (size_t)row_g * 8;
#pragma unroll
    for (int q = 0; q < 8; ++q) {
        ov[q] = make_float4(fmaf((y[q * 4 + 0] - m) * r, ws[1344 + q * 4 + 0], ws[1376 + q * 4 + 0]),
                            fmaf((y[q * 4 + 1] - m) * r, ws[1344 + q * 4 + 1], ws[1376 + q * 4 + 1]),
                            fmaf((y[q * 4 + 2] - m) * r, ws[1344 + q * 4 + 2], ws[1376 + q * 4 + 2]),
                            fmaf((y[q * 4 + 3] - m) * r, ws[1344 + q * 4 + 3], ws[1376 + q * 4 + 3]));
    }
}

extern "C" void kernel_launch(void* const* d_in, const int* in_sizes, int n_in,
                              void* d_out, int out_size, void* d_ws, size_t ws_size,
                              hipStream_t stream) {
    const float* x   = (const float*)d_in[0];
    const float* adj = (const float*)d_in[1];
    const float* W1  = (const float*)d_in[2];
    const float* b1  = (const float*)d_in[3];
    const float* W2  = (const float*)d_in[4];
    const float* b2  = (const float*)d_in[5];
    const float* g1  = (const float*)d_in[6];
    const float* be1 = (const float*)d_in[7];
    const float* g2  = (const float*)d_in[8];
    const float* be2 = (const float*)d_in[9];
    float* out = (float*)d_out;
    float* ws  = (float*)d_ws;

    gnn_prologue<<<1, 256, 0, stream>>>(adj, W1, b1, W2, b2, g1, be1, g2, be2, ws);

    const int rows = 32 * 2048 * 32;            // 2,097,152
    gnn_main<<<rows / 256, 256, 0, stream>>>(x, ws, out);
}

// Round 13
// 117.613 us; speedup vs baseline: 2.9060x; 1.0126x over previous
//
#include <hip/hip_runtime.h>

#define LN_EPS 1e-5f

// Sizes fixed by the problem: B=32, TF=2048, C=32, D=8, HID=EG=32.
// rows = B*TF*C = 2,097,152 independent rows: x[8] -> M1x+c1 -> relu -> LN ->
// M2'h+c2' -> relu -> LN -> *g2+be2. Adjacency + LN1 affine folded on device.
//
// PROVEN-ROLE RULE (r6-r11 failures, 9-point separation): MFMA arg0 MUST be
// the activation fragments read row-wise from LDS (r5 pattern) and arg1 MUST
// be the baked weight table (r5 pattern). Do not swap.
// PRECISION RULE (r12 failure, absmax 0.219): the MFMA needs the full 3-term
// hi/lo split (Ahi*Bhi + Ahi*Blo + Alo*Bhi). 2-term is ~0.2 absmax, over thr.
//
// d_ws float layout (r5-compatible):
//   [0,256)     M1pk: pair-interleaved M1, ws[p*16 + d*2 + e] = M1[2p+e][d]
//   [256,288)   c1  = A@b1   (pairs read as float2)
//   [288,1312)  M2' fp32 (bake source mirror; main kernel does not read)
//   [1312,1344) c2' = A@b2 + (A@W2)@be1
//   [1344,1376) g2
//   [1376,1408) be2
//   u16 [2816,3840)  B-frag bhi: slot (nt*64 + l15*4 + lg)*8+i =
//                    bf16hi(M2'[n=nt*16+l15][k=lg*8+i])
//   u16 [3840,4864)  B-frag blo: bf16lo residual of the same

typedef float  f32x4  __attribute__((ext_vector_type(4)));
typedef __bf16 bf16x8 __attribute__((ext_vector_type(8)));

__global__ void gnn_prologue(const float* __restrict__ adjacency,
                             const float* __restrict__ W1,
                             const float* __restrict__ b1,
                             const float* __restrict__ W2,
                             const float* __restrict__ b2,
                             const float* __restrict__ g1,
                             const float* __restrict__ be1,
                             const float* __restrict__ g2,
                             const float* __restrict__ be2,
                             float* __restrict__ ws) {
    __shared__ float dis[32];
    __shared__ float na[32][32];
    __shared__ float m2t[32][32];   // A@W2 (g1 folded at bake)
    __shared__ float m1s[32][8];
    const int t = threadIdx.x;
    if (t < 32) {
        float s = 1.0f;  // self-loop contributes 1 to the degree
        for (int j = 0; j < 32; ++j) s += adjacency[t * 32 + j];
        dis[t] = rsqrtf(s + 1e-6f);
    }
    __syncthreads();
    for (int idx = t; idx < 1024; idx += 256) {
        const int i = idx >> 5, j = idx & 31;
        const float a = adjacency[idx] + (i == j ? 1.0f : 0.0f);
        na[i][j] = dis[i] * a * dis[j];
    }
    __syncthreads();
    for (int idx = t; idx < 1024; idx += 256) {     // m2t = na @ W2
        const int i = idx >> 5, k = idx & 31;
        float a = 0.0f;
        for (int j = 0; j < 32; ++j) a += na[i][j] * W2[j * 32 + k];
        m2t[i][k] = a;
    }
    {
        const int i = t >> 3, d = t & 7;            // m1 = na @ W1 (to LDS)
        float a = 0.0f;
        for (int j = 0; j < 32; ++j) a += na[i][j] * W1[j * 8 + d];
        m1s[i][d] = a;
    }
    __syncthreads();
    for (int idx = t; idx < 1024; idx += 256)       // M2' mirror (unused by main)
        ws[288 + idx] = m2t[idx >> 5][idx & 31] * g1[idx & 31];
    if (t < 128) {                                   // M1 pk-interleaved bake
        const int p = t >> 3, d = t & 7;
        ws[p * 16 + d * 2]     = m1s[2 * p][d];
        ws[p * 16 + d * 2 + 1] = m1s[2 * p + 1][d];
    }
    if (t < 32) {
        float a1 = 0.0f, a2 = 0.0f, a3 = 0.0f;
        for (int j = 0; j < 32; ++j) {
            a1 += na[t][j] * b1[j];
            a2 += na[t][j] * b2[j];
            a3 += m2t[t][j] * be1[j];
        }
        ws[256 + t]  = a1;          // c1
        ws[1312 + t] = a2 + a3;     // c2'
        ws[1344 + t] = g2[t];
        ws[1376 + t] = be2[t];
    }
    // Bake B fragments (r5-exact): slot (nt, l15, lg) holds k = lg*8+i for
    // n = nt*16 + l15, split into bf16 hi/lo.
    if (t < 128) {
        const int nt  = t >> 6;
        const int l15 = (t >> 2) & 15;
        const int lg  = t & 3;
        const int n   = nt * 16 + l15;
        unsigned short* wsu = (unsigned short*)ws;
        for (int i = 0; i < 8; ++i) {
            const float w  = m2t[n][lg * 8 + i] * g1[lg * 8 + i];
            const __bf16 h = (__bf16)w;
            const __bf16 l = (__bf16)(w - (float)h);
            wsu[2816 + t * 8 + i] = __builtin_bit_cast(unsigned short, h);
            wsu[3840 + t * 8 + i] = __builtin_bit_cast(unsigned short, l);
        }
    }
}

// Main kernel (r5 structure): 256 threads = 4 waves; each wave owns 64 rows.
// Per-wave LDS scratch wbuf[wave][2304 floats] used twice:
//   phase A: hhat[64 rows][stride 36 floats]  (normalized h, fp32)
//   phase B: YT [32 cols][stride 68 floats]   (relu'd stage-2 out, fp32)
__global__ __launch_bounds__(256, 4) void gnn_main(
        const float* __restrict__ x,
        const float* __restrict__ ws,
        float* __restrict__ out) {
    __shared__ float wbuf[4][2304];

    const int t    = threadIdx.x;
    const int wave = t >> 6;
    const int lane = t & 63;
    const int l15  = lane & 15;
    const int lg   = lane >> 4;
    float* const hb = &wbuf[wave][0];

    // B fragments (weights as arg1 — PROVEN ROLE), baked bf16 hi/lo.
    const unsigned short* wsu = (const unsigned short*)ws;
    const int slot8 = (l15 * 4 + lg) * 8;
    bf16x8 bhi[2], blo[2];
    bhi[0] = *(const bf16x8*)(wsu + 2816 + slot8);
    bhi[1] = *(const bf16x8*)(wsu + 2816 + 512 + slot8);
    blo[0] = *(const bf16x8*)(wsu + 3840 + slot8);
    blo[1] = *(const bf16x8*)(wsu + 3840 + 512 + slot8);
    const float c2a = ws[1312 + l15];
    const float c2b = ws[1312 + 16 + l15];

    const int row_g = blockIdx.x * 256 + t;     // one row per thread
    const float4 p0 = ((const float4*)x)[row_g * 2];
    const float4 p1 = ((const float4*)x)[row_g * 2 + 1];
    const float xr[8] = {p0.x, p0.y, p0.z, p0.w, p1.x, p1.y, p1.z, p1.w};

    // stage 1: h = relu(M1 @ x + c1) on float2 pairs (v_pk_fma_f32 pattern)
    float2 hp[16];
#pragma unroll
    for (int p = 0; p < 16; ++p) hp[p] = *(const float2*)(ws + 256 + p * 2);
#pragma unroll
    for (int d = 0; d < 8; ++d) {
        const float xd = xr[d];
#pragma unroll
        for (int p = 0; p < 16; ++p) {
            const float2 w = *(const float2*)(ws + p * 16 + d * 2);
            hp[p].x = fmaf(w.x, xd, hp[p].x);
            hp[p].y = fmaf(w.y, xd, hp[p].y);
        }
    }
#pragma unroll
    for (int p = 0; p < 16; ++p) {
        hp[p].x = fmaxf(hp[p].x, 0.0f);
        hp[p].y = fmaxf(hp[p].y, 0.0f);
    }
    // LN1 normalize (affine folded into M2'/c2'), paired tree moments
    {
        float2 sa = {0, 0}, sb = {0, 0}, qa = {0, 0}, qb = {0, 0};
#pragma unroll
        for (int p = 0; p < 16; p += 2) {
            sa.x += hp[p].x;     sa.y += hp[p].y;
            sb.x += hp[p + 1].x; sb.y += hp[p + 1].y;
            qa.x = fmaf(hp[p].x, hp[p].x, qa.x);
            qa.y = fmaf(hp[p].y, hp[p].y, qa.y);
            qb.x = fmaf(hp[p + 1].x, hp[p + 1].x, qb.x);
            qb.y = fmaf(hp[p + 1].y, hp[p + 1].y, qb.y);
        }
        const float m   = ((sa.x + sa.y) + (sb.x + sb.y)) * 0.03125f;
        const float msq = ((qa.x + qa.y) + (qb.x + qb.y)) * 0.03125f;
        const float r   = rsqrtf(fmaf(-m, m, msq) + LN_EPS);
        float* dst = hb + lane * 36;            // 144 B stride: conflict-perfect
#pragma unroll
        for (int c = 0; c < 8; ++c) {
            ((float4*)dst)[c] = make_float4((hp[c * 2].x - m) * r, (hp[c * 2].y - m) * r,
                                            (hp[c * 2 + 1].x - m) * r, (hp[c * 2 + 1].y - m) * r);
        }
    }
    __syncthreads();

    // A fragments (activations as arg0 — PROVEN ROLE): A[m][k]=hhat[mt*16+m][k];
    // lane holds m=l15, k=lg*8+i. Full hi/lo split (PRECISION RULE).
    bf16x8 ahi[4], alo[4];
#pragma unroll
    for (int mt = 0; mt < 4; ++mt) {
        const float* ap = hb + (mt * 16 + l15) * 36 + lg * 8;
        const float4 a0 = ((const float4*)ap)[0];
        const float4 a1 = ((const float4*)ap)[1];
        const float av[8] = {a0.x, a0.y, a0.z, a0.w, a1.x, a1.y, a1.z, a1.w};
#pragma unroll
        for (int i = 0; i < 8; ++i) {
            const __bf16 hi = (__bf16)av[i];
            ahi[mt][i] = hi;
            alo[mt][i] = (__bf16)(av[i] - (float)hi);
        }
    }
    __syncthreads();   // all A-frag reads landed before wbuf is overwritten as YT

    // stage 2 MFMA: 4 m-tiles x 2 n-tiles, 3-term split; relu; YT write.
#pragma unroll
    for (int mt = 0; mt < 4; ++mt) {
#pragma unroll
        for (int nt = 0; nt < 2; ++nt) {
            const float c2v = nt ? c2b : c2a;
            f32x4 acc = {c2v, c2v, c2v, c2v};
            acc = __builtin_amdgcn_mfma_f32_16x16x32_bf16(ahi[mt], bhi[nt], acc, 0, 0, 0);
            acc = __builtin_amdgcn_mfma_f32_16x16x32_bf16(alo[mt], bhi[nt], acc, 0, 0, 0);
            acc = __builtin_amdgcn_mfma_f32_16x16x32_bf16(ahi[mt], blo[nt], acc, 0, 0, 0);
            // D reg j -> row (lane>>4)*4 + j, col lane&15  (r5-verified)
            float* yt = hb + (nt * 16 + l15) * 68 + mt * 16 + lg * 4;   // 272 B stride
            *((float4*)yt) = make_float4(fmaxf(acc[0], 0.0f), fmaxf(acc[1], 0.0f),
                                         fmaxf(acc[2], 0.0f), fmaxf(acc[3], 0.0f));
        }
    }
    __syncthreads();

    // LN2 read-back: lane reads its own row (2 lanes/bank -> conflict-free);
    // fused single-pass moments with tree partials.
    float y[32];
#pragma unroll
    for (int c = 0; c < 32; ++c) y[c] = hb[c * 68 + lane];
    float s0 = 0, s1 = 0, s2 = 0, s3 = 0, q0 = 0, q1 = 0, q2 = 0, q3 = 0;
#pragma unroll
    for (int i = 0; i < 32; i += 4) {
        s0 += y[i];     q0 = fmaf(y[i],     y[i],     q0);
        s1 += y[i + 1]; q1 = fmaf(y[i + 1], y[i + 1], q1);
        s2 += y[i + 2]; q2 = fmaf(y[i + 2], y[i + 2], q2);
        s3 += y[i + 3]; q3 = fmaf(y[i + 3], y[i + 3], q3);
    }
    const float m   = ((s0 + s1) + (s2 + s3)) * 0.03125f;
    const float msq = ((q0 + q1) + (q2 + q3)) * 0.03125f;
    const float r   = rsqrtf(fmaf(-m, m, msq) + LN_EPS);

    float4* ov = (float4*)out + (size_t)row_g * 8;
#pragma unroll
    for (int q = 0; q < 8; ++q) {
        ov[q] = make_float4(fmaf((y[q * 4 + 0] - m) * r, ws[1344 + q * 4 + 0], ws[1376 + q * 4 + 0]),
                            fmaf((y[q * 4 + 1] - m) * r, ws[1344 + q * 4 + 1], ws[1376 + q * 4 + 1]),
                            fmaf((y[q * 4 + 2] - m) * r, ws[1344 + q * 4 + 2], ws[1376 + q * 4 + 2]),
                            fmaf((y[q * 4 + 3] - m) * r, ws[1344 + q * 4 + 3], ws[1376 + q * 4 + 3]));
    }
}

extern "C" void kernel_launch(void* const* d_in, const int* in_sizes, int n_in,
                              void* d_out, int out_size, void* d_ws, size_t ws_size,
                              hipStream_t stream) {
    const float* x   = (const float*)d_in[0];
    const float* adj = (const float*)d_in[1];
    const float* W1  = (const float*)d_in[2];
    const float* b1  = (const float*)d_in[3];
    const float* W2  = (const float*)d_in[4];
    const float* b2  = (const float*)d_in[5];
    const float* g1  = (const float*)d_in[6];
    const float* be1 = (const float*)d_in[7];
    const float* g2  = (const float*)d_in[8];
    const float* be2 = (const float*)d_in[9];
    float* out = (float*)d_out;
    float* ws  = (float*)d_ws;

    gnn_prologue<<<1, 256, 0, stream>>>(adj, W1, b1, W2, b2, g1, be1, g2, be2, ws);

    const int rows = 32 * 2048 * 32;            // 2,097,152
    gnn_main<<<rows / 256, 256, 0, stream>>>(x, ws, out);
}

// Round 14
// 110.852 us; speedup vs baseline: 3.0832x; 1.0610x over previous
//
#include <hip/hip_runtime.h>

#define LN_EPS 1e-5f

// Sizes fixed by the problem: B=32, TF=2048, C=32, D=8, HID=EG=32.
// rows = B*TF*C = 2,097,152 independent rows: x[8] -> M1x+c1 -> relu -> LN ->
// M2'h+c2' -> relu -> LN -> *g2+be2. Adjacency + LN1 affine folded on device.
//
// PROVEN-ROLE RULE (r6-r11): MFMA arg0 = activation fragments read row-wise
// from LDS (r5 pattern); arg1 = baked weight table. Do not swap.
// PRECISION RULE (r12): full 3-term hi/lo split required (2-term = 0.219 absmax).
// r14: LDS 36.9->32 KB (5 blocks/CU) via XOR slot swizzles instead of pad
// strides; bit-identical math to r13.
//
// d_ws float layout:
//   [0,256)     M1pk: pair-interleaved M1, ws[p*16 + d*2 + e] = M1[2p+e][d]
//   [256,288)   c1  = A@b1   (pairs read as float2)
//   [1312,1344) c2' = A@b2 + (A@W2)@be1
//   [1344,1376) g2
//   [1376,1408) be2
//   u16 [2816,3840)  B-frag bhi: slot (nt*64 + l15*4 + lg)*8+i =
//                    bf16hi(M2'[n=nt*16+l15][k=lg*8+i]),  M2'=(A@W2)*diag(g1)
//   u16 [3840,4864)  B-frag blo: bf16lo residual of the same

typedef float  f32x4  __attribute__((ext_vector_type(4)));
typedef __bf16 bf16x8 __attribute__((ext_vector_type(8)));

__global__ void gnn_prologue(const float* __restrict__ adjacency,
                             const float* __restrict__ W1,
                             const float* __restrict__ b1,
                             const float* __restrict__ W2,
                             const float* __restrict__ b2,
                             const float* __restrict__ g1,
                             const float* __restrict__ be1,
                             const float* __restrict__ g2,
                             const float* __restrict__ be2,
                             float* __restrict__ ws) {
    __shared__ float dis[32];
    __shared__ float na[32][32];
    __shared__ float m2t[32][32];   // A@W2 (g1 folded at bake)
    __shared__ float m1s[32][8];
    const int t = threadIdx.x;
    if (t < 32) {
        float s = 1.0f;  // self-loop contributes 1 to the degree
        for (int j = 0; j < 32; ++j) s += adjacency[t * 32 + j];
        dis[t] = rsqrtf(s + 1e-6f);
    }
    __syncthreads();
    for (int idx = t; idx < 1024; idx += 256) {
        const int i = idx >> 5, j = idx & 31;
        const float a = adjacency[idx] + (i == j ? 1.0f : 0.0f);
        na[i][j] = dis[i] * a * dis[j];
    }
    __syncthreads();
    for (int idx = t; idx < 1024; idx += 256) {     // m2t = na @ W2
        const int i = idx >> 5, k = idx & 31;
        float a = 0.0f;
        for (int j = 0; j < 32; ++j) a += na[i][j] * W2[j * 32 + k];
        m2t[i][k] = a;
    }
    {
        const int i = t >> 3, d = t & 7;            // m1 = na @ W1 (to LDS)
        float a = 0.0f;
        for (int j = 0; j < 32; ++j) a += na[i][j] * W1[j * 8 + d];
        m1s[i][d] = a;
    }
    __syncthreads();
    if (t < 128) {                                   // M1 pk-interleaved bake
        const int p = t >> 3, d = t & 7;
        ws[p * 16 + d * 2]     = m1s[2 * p][d];
        ws[p * 16 + d * 2 + 1] = m1s[2 * p + 1][d];
    }
    if (t < 32) {
        float a1 = 0.0f, a2 = 0.0f, a3 = 0.0f;
        for (int j = 0; j < 32; ++j) {
            a1 += na[t][j] * b1[j];
            a2 += na[t][j] * b2[j];
            a3 += m2t[t][j] * be1[j];
        }
        ws[256 + t]  = a1;          // c1
        ws[1312 + t] = a2 + a3;     // c2'
        ws[1344 + t] = g2[t];
        ws[1376 + t] = be2[t];
    }
    // Bake B fragments (r5-exact): slot (nt, l15, lg) holds k = lg*8+i for
    // n = nt*16 + l15, split into bf16 hi/lo.
    if (t < 128) {
        const int nt  = t >> 6;
        const int l15 = (t >> 2) & 15;
        const int lg  = t & 3;
        const int n   = nt * 16 + l15;
        unsigned short* wsu = (unsigned short*)ws;
        for (int i = 0; i < 8; ++i) {
            const float w  = m2t[n][lg * 8 + i] * g1[lg * 8 + i];
            const __bf16 h = (__bf16)w;
            const __bf16 l = (__bf16)(w - (float)h);
            wsu[2816 + t * 8 + i] = __builtin_bit_cast(unsigned short, h);
            wsu[3840 + t * 8 + i] = __builtin_bit_cast(unsigned short, l);
        }
    }
}

// Main kernel (r13 structure, swizzled LDS): 256 threads = 4 waves, 64 rows
// per wave. Per-wave LDS = 2048 dwords (8 KB), reused twice (barrier-sep):
//   phase A: hhat[row 0..63][32 dwords], slot-swizzled: 4-dword slot c of
//            row r lives at r*32 + ((c ^ (r&7))<<2)      (bank-floor b128)
//   phase B: YT[n 0..31][64 dwords], slot-swizzled: 4-dword m-slot s of
//            channel n lives at n*64 + ((s ^ (n&15))<<2) (bank-floor)
// Block LDS = 32 KB exactly -> 5 blocks/CU (160 KiB).
__global__ __launch_bounds__(256, 5) void gnn_main(
        const float* __restrict__ x,
        const float* __restrict__ ws,
        float* __restrict__ out) {
    __shared__ __align__(16) float wbuf[4][2048];

    const int t    = threadIdx.x;
    const int wave = t >> 6;
    const int lane = t & 63;
    const int l15  = lane & 15;
    const int lg   = lane >> 4;
    float* const hb = wbuf[wave];

    // B fragments (weights as arg1 — PROVEN ROLE), baked bf16 hi/lo.
    const unsigned short* wsu = (const unsigned short*)ws;
    const int slot8 = (l15 * 4 + lg) * 8;
    bf16x8 bhi[2], blo[2];
    bhi[0] = *(const bf16x8*)(wsu + 2816 + slot8);
    bhi[1] = *(const bf16x8*)(wsu + 2816 + 512 + slot8);
    blo[0] = *(const bf16x8*)(wsu + 3840 + slot8);
    blo[1] = *(const bf16x8*)(wsu + 3840 + 512 + slot8);
    const float c2a = ws[1312 + l15];
    const float c2b = ws[1312 + 16 + l15];

    const int row_g = blockIdx.x * 256 + t;     // one row per thread
    const float4 p0 = ((const float4*)x)[row_g * 2];
    const float4 p1 = ((const float4*)x)[row_g * 2 + 1];
    const float xr[8] = {p0.x, p0.y, p0.z, p0.w, p1.x, p1.y, p1.z, p1.w};

    // stage 1: h = relu(M1 @ x + c1) on float2 pairs (v_pk_fma_f32 pattern)
    float2 hp[16];
#pragma unroll
    for (int p = 0; p < 16; ++p) hp[p] = *(const float2*)(ws + 256 + p * 2);
#pragma unroll
    for (int d = 0; d < 8; ++d) {
        const float xd = xr[d];
#pragma unroll
        for (int p = 0; p < 16; ++p) {
            const float2 w = *(const float2*)(ws + p * 16 + d * 2);
            hp[p].x = fmaf(w.x, xd, hp[p].x);
            hp[p].y = fmaf(w.y, xd, hp[p].y);
        }
    }
#pragma unroll
    for (int p = 0; p < 16; ++p) {
        hp[p].x = fmaxf(hp[p].x, 0.0f);
        hp[p].y = fmaxf(hp[p].y, 0.0f);
    }
    // LN1 normalize (affine folded into M2'/c2'), paired tree moments
    {
        float2 sa = {0, 0}, sb = {0, 0}, qa = {0, 0}, qb = {0, 0};
#pragma unroll
        for (int p = 0; p < 16; p += 2) {
            sa.x += hp[p].x;     sa.y += hp[p].y;
            sb.x += hp[p + 1].x; sb.y += hp[p + 1].y;
            qa.x = fmaf(hp[p].x, hp[p].x, qa.x);
            qa.y = fmaf(hp[p].y, hp[p].y, qa.y);
            qb.x = fmaf(hp[p + 1].x, hp[p + 1].x, qb.x);
            qb.y = fmaf(hp[p + 1].y, hp[p + 1].y, qb.y);
        }
        const float m   = ((sa.x + sa.y) + (sb.x + sb.y)) * 0.03125f;
        const float msq = ((qa.x + qa.y) + (qb.x + qb.y)) * 0.03125f;
        const float r   = rsqrtf(fmaf(-m, m, msq) + LN_EPS);
        // phase A write: row = lane, slot c swizzled by (lane&7)
        float* const dst = hb + lane * 32;
        const int key3 = lane & 7;
#pragma unroll
        for (int c = 0; c < 8; ++c) {
            *(float4*)(dst + ((c ^ key3) << 2)) =
                make_float4((hp[c * 2].x - m) * r, (hp[c * 2].y - m) * r,
                            (hp[c * 2 + 1].x - m) * r, (hp[c * 2 + 1].y - m) * r);
        }
    }
    __syncthreads();

    // A fragments (activations as arg0 — PROVEN ROLE): A[m][k]=hhat[mt*16+m][k];
    // lane holds m=l15, k=lg*8+i. Full hi/lo split (PRECISION RULE).
    bf16x8 ahi[4], alo[4];
    const int k7 = l15 & 7;   // row swizzle key: (mt*16+l15)&7 == l15&7
#pragma unroll
    for (int mt = 0; mt < 4; ++mt) {
        const float* ap = hb + (mt * 16 + l15) * 32;
        const float4 a0 = *(const float4*)(ap + (((2 * lg) ^ k7) << 2));
        const float4 a1 = *(const float4*)(ap + (((2 * lg + 1) ^ k7) << 2));
        const float av[8] = {a0.x, a0.y, a0.z, a0.w, a1.x, a1.y, a1.z, a1.w};
#pragma unroll
        for (int i = 0; i < 8; ++i) {
            const __bf16 hi = (__bf16)av[i];
            ahi[mt][i] = hi;
            alo[mt][i] = (__bf16)(av[i] - (float)hi);
        }
    }
    __syncthreads();   // all A-frag reads landed before hb is reused as YT

    // stage 2 MFMA: 4 m-tiles x 2 n-tiles, 3-term split; relu; YT write.
#pragma unroll
    for (int mt = 0; mt < 4; ++mt) {
#pragma unroll
        for (int nt = 0; nt < 2; ++nt) {
            const float c2v = nt ? c2b : c2a;
            f32x4 acc = {c2v, c2v, c2v, c2v};
            acc = __builtin_amdgcn_mfma_f32_16x16x32_bf16(ahi[mt], bhi[nt], acc, 0, 0, 0);
            acc = __builtin_amdgcn_mfma_f32_16x16x32_bf16(alo[mt], bhi[nt], acc, 0, 0, 0);
            acc = __builtin_amdgcn_mfma_f32_16x16x32_bf16(ahi[mt], blo[nt], acc, 0, 0, 0);
            // D reg j -> row (lane>>4)*4 + j, col lane&15  (r5-verified)
            // phase B write: YT[n=nt*16+l15][m-slot (mt*4+lg)] swizzled by l15
            float* yt = hb + (nt * 16 + l15) * 64 + (((mt * 4 + lg) ^ l15) << 2);
            *((float4*)yt) = make_float4(fmaxf(acc[0], 0.0f), fmaxf(acc[1], 0.0f),
                                         fmaxf(acc[2], 0.0f), fmaxf(acc[3], 0.0f));
        }
    }
    __syncthreads();

    // LN2 read-back: lane reads its own row m=lane (2 accesses/bank, free);
    // fused single-pass moments with tree partials.
    const int ms = lane >> 2, mo = lane & 3;
    float y[32];
#pragma unroll
    for (int c = 0; c < 32; ++c)
        y[c] = hb[c * 64 + ((ms ^ (c & 15)) << 2) + mo];
    float s0 = 0, s1 = 0, s2 = 0, s3 = 0, q0 = 0, q1 = 0, q2 = 0, q3 = 0;
#pragma unroll
    for (int i = 0; i < 32; i += 4) {
        s0 += y[i];     q0 = fmaf(y[i],     y[i],     q0);
        s1 += y[i + 1]; q1 = fmaf(y[i + 1], y[i + 1], q1);
        s2 += y[i + 2]; q2 = fmaf(y[i + 2], y[i + 2], q2);
        s3 += y[i + 3]; q3 = fmaf(y[i + 3], y[i + 3], q3);
    }
    const float m   = ((s0 + s1) + (s2 + s3)) * 0.03125f;
    const float msq = ((q0 + q1) + (q2 + q3)) * 0.03125f;
    const float r   = rsqrtf(fmaf(-m, m, msq) + LN_EPS);

    float4* ov = (float4*)out + (size_t)row_g * 8;
#pragma unroll
    for (int q = 0; q < 8; ++q) {
        ov[q] = make_float4(fmaf((y[q * 4 + 0] - m) * r, ws[1344 + q * 4 + 0], ws[1376 + q * 4 + 0]),
                            fmaf((y[q * 4 + 1] - m) * r, ws[1344 + q * 4 + 1], ws[1376 + q * 4 + 1]),
                            fmaf((y[q * 4 + 2] - m) * r, ws[1344 + q * 4 + 2], ws[1376 + q * 4 + 2]),
                            fmaf((y[q * 4 + 3] - m) * r, ws[1344 + q * 4 + 3], ws[1376 + q * 4 + 3]));
    }
}

extern "C" void kernel_launch(void* const* d_in, const int* in_sizes, int n_in,
                              void* d_out, int out_size, void* d_ws, size_t ws_size,
                              hipStream_t stream) {
    const float* x   = (const float*)d_in[0];
    const float* adj = (const float*)d_in[1];
    const float* W1  = (const float*)d_in[2];
    const float* b1  = (const float*)d_in[3];
    const float* W2  = (const float*)d_in[4];
    const float* b2  = (const float*)d_in[5];
    const float* g1  = (const float*)d_in[6];
    const float* be1 = (const float*)d_in[7];
    const float* g2  = (const float*)d_in[8];
    const float* be2 = (const float*)d_in[9];
    float* out = (float*)d_out;
    float* ws  = (float*)d_ws;

    gnn_prologue<<<1, 256, 0, stream>>>(adj, W1, b1, W2, b2, g1, be1, g2, be2, ws);

    const int rows = 32 * 2048 * 32;            // 2,097,152
    gnn_main<<<rows / 256, 256, 0, stream>>>(x, ws, out);
}